// Round 2
// baseline (3147.158 us; speedup 1.0000x reference)
//
#include <hip/hip_runtime.h>
#include <hip/hip_bf16.h>
#include <stdint.h>

#define Bsz 4096
#define Tsz 24
#define Isz 128
#define Hsz 512
#define Wsz 32

typedef __attribute__((ext_vector_type(8))) short short8;
typedef __attribute__((ext_vector_type(4))) float f32x4;
typedef unsigned short u16;

__device__ __forceinline__ float bf2f(u16 u) {
    union { unsigned int i; float f; } v; v.i = ((unsigned int)u) << 16; return v.f;
}
__device__ __forceinline__ u16 f2bf(float f) {
    union { float f; unsigned int i; } v; v.f = f;
    unsigned int r = v.i + 0x7fffu + ((v.i >> 16) & 1u);
    return (u16)(r >> 16);
}
__device__ __forceinline__ float sigm(float x) { return 1.0f / (1.0f + expf(-x)); }

// ---------------- f32 -> bf16 conversion ----------------------------------
__global__ __launch_bounds__(256) void convert_big(
    const float* __restrict__ src, u16* __restrict__ dst, int n)
{
    int i = (blockIdx.x * 256 + threadIdx.x) * 4;
    if (i + 4 <= n) {
        float4 v = *(const float4*)(src + i);
        dst[i + 0] = f2bf(v.x);
        dst[i + 1] = f2bf(v.y);
        dst[i + 2] = f2bf(v.z);
        dst[i + 3] = f2bf(v.w);
    }
}

struct ConvDesc { const float* src; u16* dst; int n; };
struct ConvTab { ConvDesc d[13]; };

__global__ __launch_bounds__(256) void convert_many(ConvTab tab)
{
    ConvDesc cd = tab.d[blockIdx.y];
    for (int i = (blockIdx.x * 256 + threadIdx.x) * 4; i < cd.n;
         i += gridDim.x * 256 * 4) {
        float4 v = *(const float4*)(cd.src + i);
        cd.dst[i + 0] = f2bf(v.x);
        cd.dst[i + 1] = f2bf(v.y);
        cd.dst[i + 2] = f2bf(v.z);
        cd.dst[i + 3] = f2bf(v.w);
    }
}

// Accumulate one K-segment of out[m0..m0+32, n0..n0+32] += A_seg * W_seg^T.
// A rows: global row r reads A_seg[r + shift] (zero if r+shift < 0).
// W is [Ncols, KSEG] row-major bf16.
// MFMA 16x16x32 bf16: A/B frag elem j -> k = (lane>>4)*8 + j,
// A row / B col = lane&15.  C/D: col = lane&15, row = (lane>>4)*4 + reg.
template<int KSEG>
__device__ __forceinline__ void seg_accum(
    f32x4 acc[2][2], const u16* __restrict__ Abase, int a_stride, int m0, int shift,
    const u16* __restrict__ W, int n0, int lane)
{
    const int l15 = lane & 15;
    const int klane = (lane >> 4) * 8;
#pragma unroll 4
    for (int k0 = 0; k0 < KSEG; k0 += 32) {
        short8 b0 = *(const short8*)(W + (n0 + l15) * KSEG + k0 + klane);
        short8 b1 = *(const short8*)(W + (n0 + 16 + l15) * KSEG + k0 + klane);
#pragma unroll
        for (int am = 0; am < 2; ++am) {
            int src = m0 + am * 16 + l15 + shift;
            short8 a = (short8)0;
            if (src >= 0)
                a = *(const short8*)(Abase + (long)src * a_stride + k0 + klane);
            acc[am][0] = __builtin_amdgcn_mfma_f32_16x16x32_bf16(a, b0, acc[am][0], 0, 0, 0);
            acc[am][1] = __builtin_amdgcn_mfma_f32_16x16x32_bf16(a, b1, acc[am][1], 0, 0, 0);
        }
    }
}

#define TILE_SETUP \
    const int lane = threadIdx.x & 63; \
    const int wid  = threadIdx.x >> 6; \
    const int m0 = blockIdx.x * 64 + (wid >> 1) * 32; \
    const int n0 = blockIdx.y * 64 + (wid & 1) * 32; \
    f32x4 acc[2][2]; \
    acc[0][0] = f32x4{0,0,0,0}; acc[0][1] = f32x4{0,0,0,0}; \
    acc[1][0] = f32x4{0,0,0,0}; acc[1][1] = f32x4{0,0,0,0};

// ---- stage A: h_o = sigmoid(hd@w_d^T + hw@w_w^T + hm@w_m^T + h@w_t^T)
//      and     e_t = sigmoid(xw_t@w_e^T + b_e)  (fused, K=32) --------------
__global__ __launch_bounds__(256) void stageA(
    int t, const u16* __restrict__ x, const u16* __restrict__ xw,
    const u16* __restrict__ hprev,
    const u16* __restrict__ w_d, const u16* __restrict__ w_w,
    const u16* __restrict__ w_m, const u16* __restrict__ w_t_,
    const u16* __restrict__ w_e, const float* __restrict__ b_e,
    float* __restrict__ ho_f32, u16* __restrict__ ho_bf, u16* __restrict__ e_bf)
{
    TILE_SETUP
    f32x4 ecc[2][2];
    ecc[0][0] = f32x4{0,0,0,0}; ecc[0][1] = f32x4{0,0,0,0};
    ecc[1][0] = f32x4{0,0,0,0}; ecc[1][1] = f32x4{0,0,0,0};
    const u16* xt = x + t * Isz;
    seg_accum<Isz>(acc, xt, Tsz * Isz, m0, -1,  w_d, n0, lane);
    seg_accum<Isz>(acc, xt, Tsz * Isz, m0, -7,  w_w, n0, lane);
    seg_accum<Isz>(acc, xt, Tsz * Isz, m0, -30, w_m, n0, lane);
    seg_accum<Hsz>(acc, hprev, Hsz, m0, 0, w_t_, n0, lane);
    seg_accum<Wsz>(ecc, xw + t * Wsz, Tsz * Wsz, m0, 0, w_e, n0, lane);
    const int col = lane & 15;
    const int r0 = (lane >> 4) * 4;
#pragma unroll
    for (int am = 0; am < 2; ++am)
#pragma unroll
        for (int bn = 0; bn < 2; ++bn)
#pragma unroll
            for (int i = 0; i < 4; ++i) {
                long row = m0 + am * 16 + r0 + i;
                int g = n0 + bn * 16 + col;
                float ho = sigm(acc[am][bn][i]);
                ho_f32[row * Hsz + g] = ho;
                ho_bf[row * Hsz + g] = f2bf(ho);
                float ev = sigm(ecc[am][bn][i] + b_e[g]);
                e_bf[row * Hsz + g] = f2bf(ev);
            }
}

// ---- stage B: r,z = sigmoid(x@w_*x^T + e@w_*e^T + h_o@w_*h^T + b_*) -------
//      cols [0,512) -> r (stores rh = r*h_o bf16);  [512,1024) -> z (f32)
__global__ __launch_bounds__(256) void stageB(
    int t, const u16* __restrict__ x, const u16* __restrict__ e_bf,
    const u16* __restrict__ ho_bf, const float* __restrict__ ho_f32,
    const u16* __restrict__ w_rx, const u16* __restrict__ w_re,
    const u16* __restrict__ w_rh, const float* __restrict__ b_r,
    const u16* __restrict__ w_zx, const u16* __restrict__ w_ze,
    const u16* __restrict__ w_zh, const float* __restrict__ b_z,
    u16* __restrict__ rh_bf, float* __restrict__ z_f32)
{
    TILE_SETUP
    const bool isz = (n0 >= Hsz);
    const int g0 = isz ? n0 - Hsz : n0;
    const u16* Wx = isz ? w_zx : w_rx;
    const u16* We = isz ? w_ze : w_re;
    const u16* Wh = isz ? w_zh : w_rh;
    const float* bias = isz ? b_z : b_r;
    seg_accum<Isz>(acc, x + t * Isz, Tsz * Isz, m0, 0, Wx, g0, lane);
    seg_accum<Hsz>(acc, e_bf, Hsz, m0, 0, We, g0, lane);
    seg_accum<Hsz>(acc, ho_bf, Hsz, m0, 0, Wh, g0, lane);
    const int col = lane & 15;
    const int r0 = (lane >> 4) * 4;
#pragma unroll
    for (int am = 0; am < 2; ++am)
#pragma unroll
        for (int bn = 0; bn < 2; ++bn)
#pragma unroll
            for (int i = 0; i < 4; ++i) {
                long row = m0 + am * 16 + r0 + i;
                int g = g0 + bn * 16 + col;
                float s = sigm(acc[am][bn][i] + bias[g]);
                if (!isz) {
                    float rh = s * ho_f32[row * Hsz + g];
                    rh_bf[row * Hsz + g] = f2bf(rh);
                } else {
                    z_f32[row * Hsz + g] = s;
                }
            }
}

// ---- stage C: h_tilde = tanh(x@w_hx^T + rh@w_hh^T + b_h);
//      h_next = (1-z)*h_o + z*h_tilde; write f32 out[:,t,:] and bf16 state --
__global__ __launch_bounds__(256) void stageC(
    int t, const u16* __restrict__ x, const u16* __restrict__ rh_bf,
    const u16* __restrict__ w_hx, const u16* __restrict__ w_hh,
    const float* __restrict__ b_h, const float* __restrict__ z_f32,
    const float* __restrict__ ho_f32, float* __restrict__ out,
    u16* __restrict__ hstate)
{
    TILE_SETUP
    seg_accum<Isz>(acc, x + t * Isz, Tsz * Isz, m0, 0, w_hx, n0, lane);
    seg_accum<Hsz>(acc, rh_bf, Hsz, m0, 0, w_hh, n0, lane);
    const int col = lane & 15;
    const int r0 = (lane >> 4) * 4;
#pragma unroll
    for (int am = 0; am < 2; ++am)
#pragma unroll
        for (int bn = 0; bn < 2; ++bn)
#pragma unroll
            for (int i = 0; i < 4; ++i) {
                long row = m0 + am * 16 + r0 + i;
                int g = n0 + bn * 16 + col;
                float ht = tanhf(acc[am][bn][i] + b_h[g]);
                float z = z_f32[row * Hsz + g];
                float ho = ho_f32[row * Hsz + g];
                float hn = (1.0f - z) * ho + z * ht;
                out[(row * Tsz + t) * Hsz + g] = hn;
                hstate[row * Hsz + g] = f2bf(hn);
            }
}

extern "C" void kernel_launch(void* const* d_in, const int* in_sizes, int n_in,
                              void* d_out, int out_size, void* d_ws, size_t ws_size,
                              hipStream_t stream) {
    const float* x_f    = (const float*)d_in[0];
    const float* xw_f   = (const float*)d_in[1];
    const float* w_rx_f = (const float*)d_in[2];
    const float* w_rh_f = (const float*)d_in[3];
    const float* w_re_f = (const float*)d_in[4];
    const float* b_r    = (const float*)d_in[5];
    const float* w_zx_f = (const float*)d_in[6];
    const float* w_zh_f = (const float*)d_in[7];
    const float* w_ze_f = (const float*)d_in[8];
    const float* b_z    = (const float*)d_in[9];
    const float* w_hx_f = (const float*)d_in[10];
    const float* w_hh_f = (const float*)d_in[11];
    const float* b_h    = (const float*)d_in[12];
    const float* w_d_f  = (const float*)d_in[13];
    const float* w_w_f  = (const float*)d_in[14];
    const float* w_m_f  = (const float*)d_in[15];
    const float* w_t_f  = (const float*)d_in[16];
    const float* w_e_f  = (const float*)d_in[17];
    const float* b_e    = (const float*)d_in[18];
    float* out = (float*)d_out;

    // ---- workspace layout (all 256B aligned) ----
    char* ws = (char*)d_ws;
    size_t off = 0;
    auto alloc = [&](size_t bytes) {
        size_t o = off; off = (off + bytes + 255) & ~(size_t)255; return o;
    };
    const size_t nx  = (size_t)Bsz * Tsz * Isz;   // 12,582,912
    const size_t nxw = (size_t)Bsz * Tsz * Wsz;   //  3,145,728
    const size_t nBH = (size_t)Bsz * Hsz;         //  2,097,152

    u16* x_bf   = (u16*)(ws + alloc(nx * 2));
    u16* xw_bf  = (u16*)(ws + alloc(nxw * 2));
    u16* w_rx   = (u16*)(ws + alloc(Hsz * Isz * 2));
    u16* w_rh   = (u16*)(ws + alloc(Hsz * Hsz * 2));
    u16* w_re   = (u16*)(ws + alloc(Hsz * Hsz * 2));
    u16* w_zx   = (u16*)(ws + alloc(Hsz * Isz * 2));
    u16* w_zh   = (u16*)(ws + alloc(Hsz * Hsz * 2));
    u16* w_ze   = (u16*)(ws + alloc(Hsz * Hsz * 2));
    u16* w_hx   = (u16*)(ws + alloc(Hsz * Isz * 2));
    u16* w_hh   = (u16*)(ws + alloc(Hsz * Hsz * 2));
    u16* w_d    = (u16*)(ws + alloc(Hsz * Isz * 2));
    u16* w_w    = (u16*)(ws + alloc(Hsz * Isz * 2));
    u16* w_m    = (u16*)(ws + alloc(Hsz * Isz * 2));
    u16* w_t    = (u16*)(ws + alloc(Hsz * Hsz * 2));
    u16* w_e    = (u16*)(ws + alloc(Hsz * Wsz * 2));
    u16* e_bf   = (u16*)(ws + alloc(nBH * 2));
    float* ho_f32 = (float*)(ws + alloc(nBH * 4));
    float* z_f32  = (float*)(ws + alloc(nBH * 4));
    u16* ho_bf  = (u16*)(ws + alloc(nBH * 2));
    u16* rh_bf  = (u16*)(ws + alloc(nBH * 2));
    u16* h_bf   = (u16*)(ws + alloc(nBH * 2));

    // ---- f32 -> bf16 conversions ----
    convert_big<<<(int)(nx / 1024), 256, 0, stream>>>(x_f, x_bf, (int)nx);
    convert_big<<<(int)(nxw / 1024), 256, 0, stream>>>(xw_f, xw_bf, (int)nxw);

    ConvTab tab;
    tab.d[0]  = { w_rx_f, w_rx, Hsz * Isz };
    tab.d[1]  = { w_rh_f, w_rh, Hsz * Hsz };
    tab.d[2]  = { w_re_f, w_re, Hsz * Hsz };
    tab.d[3]  = { w_zx_f, w_zx, Hsz * Isz };
    tab.d[4]  = { w_zh_f, w_zh, Hsz * Hsz };
    tab.d[5]  = { w_ze_f, w_ze, Hsz * Hsz };
    tab.d[6]  = { w_hx_f, w_hx, Hsz * Isz };
    tab.d[7]  = { w_hh_f, w_hh, Hsz * Hsz };
    tab.d[8]  = { w_d_f,  w_d,  Hsz * Isz };
    tab.d[9]  = { w_w_f,  w_w,  Hsz * Isz };
    tab.d[10] = { w_m_f,  w_m,  Hsz * Isz };
    tab.d[11] = { w_t_f,  w_t,  Hsz * Hsz };
    tab.d[12] = { w_e_f,  w_e,  Hsz * Wsz };
    convert_many<<<dim3(256, 13), 256, 0, stream>>>(tab);

    // h0 = 0
    hipMemsetAsync(h_bf, 0, nBH * sizeof(u16), stream);

    for (int t = 0; t < Tsz; ++t) {
        stageA<<<dim3(Bsz / 64, Hsz / 64), 256, 0, stream>>>(
            t, x_bf, xw_bf, h_bf, w_d, w_w, w_m, w_t, w_e, b_e,
            ho_f32, ho_bf, e_bf);
        stageB<<<dim3(Bsz / 64, 2 * Hsz / 64), 256, 0, stream>>>(
            t, x_bf, e_bf, ho_bf, ho_f32, w_rx, w_re, w_rh, b_r,
            w_zx, w_ze, w_zh, b_z, rh_bf, z_f32);
        stageC<<<dim3(Bsz / 64, Hsz / 64), 256, 0, stream>>>(
            t, x_bf, rh_bf, w_hx, w_hh, b_h, z_f32, ho_f32, out, h_bf);
    }
}

// Round 3
// 2487.516 us; speedup vs baseline: 1.2652x; 1.2652x over previous
//
#include <hip/hip_runtime.h>
#include <stdint.h>

#define Bsz 4096
#define Tsz 24
#define Isz 128
#define Hsz 512
#define Wsz 32
#define Msz (Bsz * Tsz)   // 98304 flat rows (b*T+t)

typedef __attribute__((ext_vector_type(8))) short short8;
typedef __attribute__((ext_vector_type(4))) float f32x4;
typedef unsigned short u16;

__device__ __forceinline__ float bf2f(u16 u) {
    union { unsigned int i; float f; } v; v.i = ((unsigned int)u) << 16; return v.f;
}
__device__ __forceinline__ u16 f2bf(float f) {
    union { float f; unsigned int i; } v; v.f = f;
    unsigned int r = v.i + 0x7fffu + ((v.i >> 16) & 1u);
    return (u16)(r >> 16);
}
__device__ __forceinline__ float sigm(float x) { return 1.0f / (1.0f + expf(-x)); }

// async global->LDS, 16B per lane; LDS dest = wave-uniform base + lane*16
#define GLOAD_LDS16(SRC, DST) \
    __builtin_amdgcn_global_load_lds( \
        (__attribute__((address_space(1))) void*)(SRC), \
        (__attribute__((address_space(3))) void*)(DST), 16, 0, 0)

// ---------------- f32 -> bf16 conversion ----------------------------------
__global__ __launch_bounds__(256) void convert_big(
    const float* __restrict__ src, u16* __restrict__ dst, int n)
{
    int i = (blockIdx.x * 256 + threadIdx.x) * 4;
    if (i + 4 <= n) {
        float4 v = *(const float4*)(src + i);
        dst[i + 0] = f2bf(v.x); dst[i + 1] = f2bf(v.y);
        dst[i + 2] = f2bf(v.z); dst[i + 3] = f2bf(v.w);
    }
}

struct ConvDesc { const float* src; u16* dst; int n; };
struct ConvTab { ConvDesc d[13]; };

__global__ __launch_bounds__(256) void convert_many(ConvTab tab)
{
    ConvDesc cd = tab.d[blockIdx.y];
    for (int i = (blockIdx.x * 256 + threadIdx.x) * 4; i < cd.n;
         i += gridDim.x * 256 * 4) {
        float4 v = *(const float4*)(cd.src + i);
        cd.dst[i + 0] = f2bf(v.x); cd.dst[i + 1] = f2bf(v.y);
        cd.dst[i + 2] = f2bf(v.z); cd.dst[i + 3] = f2bf(v.w);
    }
}

// ======================= LDS-staged GEMM core ==============================
// Block tile 128x128, BK=64, 256 thr (4 waves, each 64x64 = 4x4 MFMA tiles).
// LDS tiles [128 rows][8 granules of 16B], granule col XOR-swizzled by row&7,
// applied on BOTH the global source address and the ds_read address.
struct Seg { const u16* A; int astr; int shift; const u16* W; int wstr; int nkb; };

__device__ __forceinline__ void stage_half(
    u16* ldsT, const u16* gbase, int rstr, int rvf,
    const u16* zerobuf, int wid, int lane)
{
#pragma unroll
    for (int q = 0; q < 4; ++q) {
        int c   = wid * 4 + q;       // chunk 0..15 (1KB each)
        int lin = c * 64 + lane;     // granule id 0..1023
        int row = lin >> 3;
        int gc  = lin & 7;
        const u16* src = (row >= rvf)
            ? (gbase + (long)row * rstr + ((gc ^ (row & 7)) << 3))
            : zerobuf;
        GLOAD_LDS16(src, ldsT + c * 512);
    }
}

__device__ __forceinline__ void stage_step(
    const Seg* segs, int nseg, int kb, u16* ldsA, u16* ldsB,
    int m0, int n0, const u16* zerobuf, int wid, int lane)
{
    Seg s = segs[0];
    int kloc = kb;
    if (nseg > 1 && kloc >= s.nkb) {
        kloc -= s.nkb; s = segs[1];
        if (nseg > 2 && kloc >= s.nkb) { kloc -= s.nkb; s = segs[2]; }
    }
    int base_row = m0 + s.shift;
    int rvf = base_row < 0 ? -base_row : 0;
    stage_half(ldsA, s.A + (long)base_row * s.astr + kloc * 64, s.astr, rvf,
               zerobuf, wid, lane);
    stage_half(ldsB, s.W + (long)n0 * s.wstr + kloc * 64, s.wstr, 0,
               zerobuf, wid, lane);
}

__device__ __forceinline__ void compute_tile(
    f32x4 acc[4][4], const u16* Ab, const u16* Bb, int wr, int wc, int lane)
{
    const int l15 = lane & 15;
    const int hi = lane >> 4;
#pragma unroll
    for (int ks = 0; ks < 2; ++ks) {
        int kg = ks * 4 + hi;  // granule 0..7
        short8 a[4], b[4];
#pragma unroll
        for (int am = 0; am < 4; ++am) {
            int row = wr * 64 + am * 16 + l15;
            a[am] = *(const short8*)(Ab + row * 64 + ((kg ^ (row & 7)) << 3));
        }
#pragma unroll
        for (int bn = 0; bn < 4; ++bn) {
            int row = wc * 64 + bn * 16 + l15;
            b[bn] = *(const short8*)(Bb + row * 64 + ((kg ^ (row & 7)) << 3));
        }
#pragma unroll
        for (int am = 0; am < 4; ++am)
#pragma unroll
            for (int bn = 0; bn < 4; ++bn)
                acc[am][bn] = __builtin_amdgcn_mfma_f32_16x16x32_bf16(
                    a[am], b[bn], acc[am][bn], 0, 0, 0);
    }
}

// m97-style single-barrier-per-K-step double-buffered loop
#define GEMM_CORE(SEGS, NSEG, M0, N0W)                                          \
    __shared__ u16 lds[2][2][128 * 64];                                         \
    const int lane = threadIdx.x & 63;                                          \
    const int wid  = threadIdx.x >> 6;                                          \
    const int wr = wid >> 1, wc = wid & 1;                                      \
    f32x4 acc[4][4];                                                            \
    _Pragma("unroll") for (int i_ = 0; i_ < 4; ++i_)                            \
    _Pragma("unroll") for (int j_ = 0; j_ < 4; ++j_)                            \
        acc[i_][j_] = f32x4{0, 0, 0, 0};                                        \
    int nkb = 0;                                                                \
    for (int s_ = 0; s_ < (NSEG); ++s_) nkb += (SEGS)[s_].nkb;                  \
    stage_step((SEGS), (NSEG), 0, lds[0][0], lds[0][1], (M0), (N0W),            \
               zerobuf, wid, lane);                                             \
    int cur = 0;                                                                \
    for (int kb = 0; kb < nkb; ++kb) {                                          \
        __syncthreads();                                                        \
        if (kb + 1 < nkb)                                                       \
            stage_step((SEGS), (NSEG), kb + 1, lds[cur ^ 1][0],                 \
                       lds[cur ^ 1][1], (M0), (N0W), zerobuf, wid, lane);       \
        compute_tile(acc, lds[cur][0], lds[cur][1], wr, wc, lane);              \
        cur ^= 1;                                                               \
    }

// ---------------- e = sigmoid(xw @ w_e^T + b_e), direct (K=32) -------------
__global__ __launch_bounds__(256) void ekernel(
    const u16* __restrict__ xw, const u16* __restrict__ w_e,
    const float* __restrict__ b_e, u16* __restrict__ eout)
{
    const int lane = threadIdx.x & 63;
    const int wid  = threadIdx.x >> 6;
    const int m0 = blockIdx.x * 64 + (wid >> 1) * 32;
    const int n0 = blockIdx.y * 64 + (wid & 1) * 32;
    f32x4 acc[2][2];
    acc[0][0] = f32x4{0,0,0,0}; acc[0][1] = f32x4{0,0,0,0};
    acc[1][0] = f32x4{0,0,0,0}; acc[1][1] = f32x4{0,0,0,0};
    const int l15 = lane & 15;
    const int klane = (lane >> 4) * 8;
    short8 b0 = *(const short8*)(w_e + (n0 + l15) * Wsz + klane);
    short8 b1 = *(const short8*)(w_e + (n0 + 16 + l15) * Wsz + klane);
#pragma unroll
    for (int am = 0; am < 2; ++am) {
        short8 a = *(const short8*)(xw + (long)(m0 + am * 16 + l15) * Wsz + klane);
        acc[am][0] = __builtin_amdgcn_mfma_f32_16x16x32_bf16(a, b0, acc[am][0], 0, 0, 0);
        acc[am][1] = __builtin_amdgcn_mfma_f32_16x16x32_bf16(a, b1, acc[am][1], 0, 0, 0);
    }
    const int col = lane & 15;
    const int r0 = (lane >> 4) * 4;
#pragma unroll
    for (int am = 0; am < 2; ++am)
#pragma unroll
        for (int bn = 0; bn < 2; ++bn)
#pragma unroll
            for (int i = 0; i < 4; ++i) {
                long row = m0 + am * 16 + r0 + i;
                int g = n0 + bn * 16 + col;
                eout[row * Hsz + g] = f2bf(sigm(acc[am][bn][i] + b_e[g]));
            }
}

// ---------------- pre-pass: pre[:, group*512 + g] -------------------------
// g0: pre_o = hd@w_d + hw@w_w + hm@w_m        (shifts -T,-7T,-30T rows)
// g1: pre_r = x@w_rx + e@w_re + b_r
// g2: pre_z = x@w_zx + e@w_ze + b_z
// g3: pre_h = x@w_hx + b_h
__global__ __launch_bounds__(256, 2) void prepass_kernel(
    const u16* __restrict__ x, const u16* __restrict__ e,
    const u16* __restrict__ w_d, const u16* __restrict__ w_w,
    const u16* __restrict__ w_m, const u16* __restrict__ w_rx,
    const u16* __restrict__ w_re, const u16* __restrict__ w_zx,
    const u16* __restrict__ w_ze, const u16* __restrict__ w_hx,
    const float* __restrict__ b_r, const float* __restrict__ b_z,
    const float* __restrict__ b_h,
    const u16* __restrict__ zerobuf, u16* __restrict__ pre)
{
    const int m0 = blockIdx.x * 128;
    const int y = blockIdx.y;
    const int group = y >> 2;
    const int nin = (y & 3) * 128;
    Seg segs[3];
    int nseg;
    const float* bias = nullptr;
    if (group == 0) {
        segs[0] = { x, Isz, -1 * Tsz,  w_d, Isz, Isz / 64 };
        segs[1] = { x, Isz, -7 * Tsz,  w_w, Isz, Isz / 64 };
        segs[2] = { x, Isz, -30 * Tsz, w_m, Isz, Isz / 64 };
        nseg = 3;
    } else if (group == 1) {
        segs[0] = { x, Isz, 0, w_rx, Isz, Isz / 64 };
        segs[1] = { e, Hsz, 0, w_re, Hsz, Hsz / 64 };
        nseg = 2; bias = b_r;
    } else if (group == 2) {
        segs[0] = { x, Isz, 0, w_zx, Isz, Isz / 64 };
        segs[1] = { e, Hsz, 0, w_ze, Hsz, Hsz / 64 };
        nseg = 2; bias = b_z;
    } else {
        segs[0] = { x, Isz, 0, w_hx, Isz, Isz / 64 };
        nseg = 1; bias = b_h;
    }
    GEMM_CORE(segs, nseg, m0, nin)
    const int l15 = lane & 15, hi4 = (lane >> 4) * 4;
#pragma unroll
    for (int am = 0; am < 4; ++am)
#pragma unroll
        for (int bn = 0; bn < 4; ++bn) {
            int colH = nin + wc * 64 + bn * 16 + l15;
            float bv = bias ? bias[colH] : 0.0f;
#pragma unroll
            for (int i = 0; i < 4; ++i) {
                long row = m0 + wr * 64 + am * 16 + hi4 + i;
                pre[row * 2048 + group * 512 + colH] = f2bf(acc[am][bn][i] + bv);
            }
        }
}

// ---------------- recurrent stages -----------------------------------------
__global__ __launch_bounds__(256, 2) void stepA_kernel(
    int t, const u16* __restrict__ h, const u16* __restrict__ w_t_,
    const u16* __restrict__ pre, const u16* __restrict__ zerobuf,
    u16* __restrict__ ho)
{
    const int m0 = blockIdx.x * 128;
    const int nb = blockIdx.y * 128;
    Seg segs[1] = { { h, Hsz, 0, w_t_, Hsz, Hsz / 64 } };
    GEMM_CORE(segs, 1, m0, nb)
    const int l15 = lane & 15, hi4 = (lane >> 4) * 4;
#pragma unroll
    for (int am = 0; am < 4; ++am)
#pragma unroll
        for (int bn = 0; bn < 4; ++bn) {
            int g = nb + wc * 64 + bn * 16 + l15;
#pragma unroll
            for (int i = 0; i < 4; ++i) {
                long row = m0 + wr * 64 + am * 16 + hi4 + i;
                long prow = row * Tsz + t;
                float v = sigm(acc[am][bn][i] + bf2f(pre[prow * 2048 + g]));
                ho[row * Hsz + g] = f2bf(v);
            }
        }
}

__global__ __launch_bounds__(256, 2) void stepB_kernel(
    int t, const u16* __restrict__ ho, const u16* __restrict__ w_rh,
    const u16* __restrict__ w_zh, const u16* __restrict__ pre,
    const u16* __restrict__ zerobuf, u16* __restrict__ rh,
    u16* __restrict__ zout)
{
    const int m0 = blockIdx.x * 128;
    const bool isz = blockIdx.y >= 4;
    const int nb = (blockIdx.y & 3) * 128;
    Seg segs[1] = { { ho, Hsz, 0, isz ? w_zh : w_rh, Hsz, Hsz / 64 } };
    GEMM_CORE(segs, 1, m0, nb)
    const int preoff = isz ? 1024 : 512;
    const int l15 = lane & 15, hi4 = (lane >> 4) * 4;
#pragma unroll
    for (int am = 0; am < 4; ++am)
#pragma unroll
        for (int bn = 0; bn < 4; ++bn) {
            int g = nb + wc * 64 + bn * 16 + l15;
#pragma unroll
            for (int i = 0; i < 4; ++i) {
                long row = m0 + wr * 64 + am * 16 + hi4 + i;
                long prow = row * Tsz + t;
                float v = sigm(acc[am][bn][i] + bf2f(pre[prow * 2048 + preoff + g]));
                if (isz) zout[row * Hsz + g] = f2bf(v);
                else     rh[row * Hsz + g] = f2bf(v * bf2f(ho[row * Hsz + g]));
            }
        }
}

__global__ __launch_bounds__(256, 2) void stepC_kernel(
    int t, const u16* __restrict__ rh, const u16* __restrict__ w_hh,
    const u16* __restrict__ pre, const u16* __restrict__ ho,
    const u16* __restrict__ zv, const u16* __restrict__ zerobuf,
    float* __restrict__ out, u16* __restrict__ h)
{
    const int m0 = blockIdx.x * 128;
    const int nb = blockIdx.y * 128;
    Seg segs[1] = { { rh, Hsz, 0, w_hh, Hsz, Hsz / 64 } };
    GEMM_CORE(segs, 1, m0, nb)
    const int l15 = lane & 15, hi4 = (lane >> 4) * 4;
#pragma unroll
    for (int am = 0; am < 4; ++am)
#pragma unroll
        for (int bn = 0; bn < 4; ++bn) {
            int g = nb + wc * 64 + bn * 16 + l15;
#pragma unroll
            for (int i = 0; i < 4; ++i) {
                long row = m0 + wr * 64 + am * 16 + hi4 + i;
                long prow = row * Tsz + t;
                float ht = tanhf(acc[am][bn][i] + bf2f(pre[prow * 2048 + 1536 + g]));
                float z = bf2f(zv[row * Hsz + g]);
                float hov = bf2f(ho[row * Hsz + g]);
                float hn = (1.0f - z) * hov + z * ht;
                out[prow * Hsz + g] = hn;
                h[row * Hsz + g] = f2bf(hn);
            }
        }
}

extern "C" void kernel_launch(void* const* d_in, const int* in_sizes, int n_in,
                              void* d_out, int out_size, void* d_ws, size_t ws_size,
                              hipStream_t stream) {
    const float* x_f    = (const float*)d_in[0];
    const float* xw_f   = (const float*)d_in[1];
    const float* w_rx_f = (const float*)d_in[2];
    const float* w_rh_f = (const float*)d_in[3];
    const float* w_re_f = (const float*)d_in[4];
    const float* b_r    = (const float*)d_in[5];
    const float* w_zx_f = (const float*)d_in[6];
    const float* w_zh_f = (const float*)d_in[7];
    const float* w_ze_f = (const float*)d_in[8];
    const float* b_z    = (const float*)d_in[9];
    const float* w_hx_f = (const float*)d_in[10];
    const float* w_hh_f = (const float*)d_in[11];
    const float* b_h    = (const float*)d_in[12];
    const float* w_d_f  = (const float*)d_in[13];
    const float* w_w_f  = (const float*)d_in[14];
    const float* w_m_f  = (const float*)d_in[15];
    const float* w_t_f  = (const float*)d_in[16];
    const float* w_e_f  = (const float*)d_in[17];
    const float* b_e    = (const float*)d_in[18];
    float* out = (float*)d_out;

    char* ws = (char*)d_ws;
    size_t off = 0;
    auto alloc = [&](size_t bytes) {
        size_t o = off; off = (off + bytes + 255) & ~(size_t)255; return o;
    };
    const size_t nx  = (size_t)Msz * Isz;   // 12,582,912
    const size_t nxw = (size_t)Msz * Wsz;   //  3,145,728
    const size_t nBH = (size_t)Bsz * Hsz;   //  2,097,152

    u16* x_bf  = (u16*)(ws + alloc(nx * 2));
    u16* xw_bf = (u16*)(ws + alloc(nxw * 2));
    u16* w_rx  = (u16*)(ws + alloc(Hsz * Isz * 2));
    u16* w_rh  = (u16*)(ws + alloc(Hsz * Hsz * 2));
    u16* w_re  = (u16*)(ws + alloc(Hsz * Hsz * 2));
    u16* w_zx  = (u16*)(ws + alloc(Hsz * Isz * 2));
    u16* w_zh  = (u16*)(ws + alloc(Hsz * Hsz * 2));
    u16* w_ze  = (u16*)(ws + alloc(Hsz * Hsz * 2));
    u16* w_hx  = (u16*)(ws + alloc(Hsz * Isz * 2));
    u16* w_hh  = (u16*)(ws + alloc(Hsz * Hsz * 2));
    u16* w_d   = (u16*)(ws + alloc(Hsz * Isz * 2));
    u16* w_w   = (u16*)(ws + alloc(Hsz * Isz * 2));
    u16* w_m   = (u16*)(ws + alloc(Hsz * Isz * 2));
    u16* w_t   = (u16*)(ws + alloc(Hsz * Hsz * 2));
    u16* w_e   = (u16*)(ws + alloc(Hsz * Wsz * 2));
    u16* e_bf  = (u16*)(ws + alloc((size_t)Msz * Hsz * 2));   // 96 MB
    u16* pre   = (u16*)(ws + alloc((size_t)Msz * 2048 * 2));  // 384 MB
    u16* ho_bf = (u16*)(ws + alloc(nBH * 2));
    u16* rh_bf = (u16*)(ws + alloc(nBH * 2));
    u16* z_bf  = (u16*)(ws + alloc(nBH * 2));
    u16* h_bf  = (u16*)(ws + alloc(nBH * 2));
    u16* zerobuf = (u16*)(ws + alloc(256));

    // conversions
    convert_big<<<(int)(nx / 1024), 256, 0, stream>>>(x_f, x_bf, (int)nx);
    convert_big<<<(int)(nxw / 1024), 256, 0, stream>>>(xw_f, xw_bf, (int)nxw);
    ConvTab tab;
    tab.d[0]  = { w_rx_f, w_rx, Hsz * Isz };
    tab.d[1]  = { w_rh_f, w_rh, Hsz * Hsz };
    tab.d[2]  = { w_re_f, w_re, Hsz * Hsz };
    tab.d[3]  = { w_zx_f, w_zx, Hsz * Isz };
    tab.d[4]  = { w_zh_f, w_zh, Hsz * Hsz };
    tab.d[5]  = { w_ze_f, w_ze, Hsz * Hsz };
    tab.d[6]  = { w_hx_f, w_hx, Hsz * Isz };
    tab.d[7]  = { w_hh_f, w_hh, Hsz * Hsz };
    tab.d[8]  = { w_d_f,  w_d,  Hsz * Isz };
    tab.d[9]  = { w_w_f,  w_w,  Hsz * Isz };
    tab.d[10] = { w_m_f,  w_m,  Hsz * Isz };
    tab.d[11] = { w_t_f,  w_t,  Hsz * Hsz };
    tab.d[12] = { w_e_f,  w_e,  Hsz * Wsz };
    convert_many<<<dim3(256, 13), 256, 0, stream>>>(tab);

    hipMemsetAsync(h_bf, 0, nBH * sizeof(u16), stream);
    hipMemsetAsync(zerobuf, 0, 256, stream);

    // e = sigmoid(xw @ w_e^T + b_e)  [98304 x 512]
    ekernel<<<dim3(Msz / 64, Hsz / 64), 256, 0, stream>>>(xw_bf, w_e, b_e, e_bf);

    // pre-pass: all input-only projections [98304 x 2048]
    prepass_kernel<<<dim3(Msz / 128, 16), 256, 0, stream>>>(
        x_bf, e_bf, w_d, w_w, w_m, w_rx, w_re, w_zx, w_ze, w_hx,
        b_r, b_z, b_h, zerobuf, pre);

    // recurrence: 4 H x H GEMMs per step in 3 kernels
    for (int t = 0; t < Tsz; ++t) {
        stepA_kernel<<<dim3(Bsz / 128, Hsz / 128), 256, 0, stream>>>(
            t, h_bf, w_t, pre, zerobuf, ho_bf);
        stepB_kernel<<<dim3(Bsz / 128, 2 * Hsz / 128), 256, 0, stream>>>(
            t, ho_bf, w_rh, w_zh, pre, zerobuf, rh_bf, z_bf);
        stepC_kernel<<<dim3(Bsz / 128, Hsz / 128), 256, 0, stream>>>(
            t, rh_bf, w_hh, pre, ho_bf, z_bf, zerobuf, out, h_bf);
    }
}

// Round 5
// 2451.940 us; speedup vs baseline: 1.2835x; 1.0145x over previous
//
#include <hip/hip_runtime.h>
#include <stdint.h>

#define Bsz 4096
#define Tsz 24
#define Isz 128
#define Hsz 512
#define Wsz 32
#define Msz (Bsz * Tsz)   // 98304 flat rows (b*T+t)

typedef __attribute__((ext_vector_type(8))) short short8;
typedef __attribute__((ext_vector_type(4))) float f32x4;
typedef unsigned short u16;

__device__ __forceinline__ float bf2f(u16 u) {
    union { unsigned int i; float f; } v; v.i = ((unsigned int)u) << 16; return v.f;
}
__device__ __forceinline__ u16 f2bf(float f) {
    union { float f; unsigned int i; } v; v.f = f;
    unsigned int r = v.i + 0x7fffu + ((v.i >> 16) & 1u);
    return (u16)(r >> 16);
}
__device__ __forceinline__ float sigm(float x) { return 1.0f / (1.0f + expf(-x)); }

__device__ __forceinline__ f32x4 MF(short8 a, short8 b, f32x4 c) {
    return __builtin_amdgcn_mfma_f32_16x16x32_bf16(a, b, c, 0, 0, 0);
}

#define GLOAD_LDS16(SRC, DST) \
    __builtin_amdgcn_global_load_lds( \
        (__attribute__((address_space(1))) void*)(SRC), \
        (__attribute__((address_space(3))) void*)(DST), 16, 0, 0)

// ---------------- f32 -> bf16 conversion ----------------------------------
__global__ __launch_bounds__(256) void convert_big(
    const float* __restrict__ src, u16* __restrict__ dst, int n)
{
    int i = (blockIdx.x * 256 + threadIdx.x) * 4;
    if (i + 4 <= n) {
        float4 v = *(const float4*)(src + i);
        dst[i + 0] = f2bf(v.x); dst[i + 1] = f2bf(v.y);
        dst[i + 2] = f2bf(v.z); dst[i + 3] = f2bf(v.w);
    }
}

struct ConvDesc { const float* src; u16* dst; int n; };
struct ConvTab { ConvDesc d[13]; };

__global__ __launch_bounds__(256) void convert_many(ConvTab tab)
{
    ConvDesc cd = tab.d[blockIdx.y];
    for (int i = (blockIdx.x * 256 + threadIdx.x) * 4; i < cd.n;
         i += gridDim.x * 256 * 4) {
        float4 v = *(const float4*)(cd.src + i);
        cd.dst[i + 0] = f2bf(v.x); cd.dst[i + 1] = f2bf(v.y);
        cd.dst[i + 2] = f2bf(v.z); cd.dst[i + 3] = f2bf(v.w);
    }
}

// ======================= prepass GEMM machinery (r3-exact) =================
// Block tile 128x128, BK=64, 256 thr (4 waves of 64x64). XOR-granule swizzle
// applied on BOTH global source (pre-swizzle) and ds_read (rule #21).
struct Seg { const u16* A; int astr; int shift; const u16* W; int wstr; int nkb; };

__device__ __forceinline__ void stage_half(
    u16* ldsT, const u16* gbase, int rstr, int rvf,
    const u16* zerobuf, int wid, int lane)
{
#pragma unroll
    for (int q = 0; q < 4; ++q) {
        int c   = wid * 4 + q;
        int lin = c * 64 + lane;
        int row = lin >> 3;
        int gc  = lin & 7;
        const u16* src = (row >= rvf)
            ? (gbase + (long)row * rstr + ((gc ^ (row & 7)) << 3))
            : zerobuf;
        GLOAD_LDS16(src, ldsT + c * 512);
    }
}

__device__ __forceinline__ void stage_step(
    const Seg* segs, int nseg, int kb, u16* ldsA, u16* ldsB,
    int m0, int n0, const u16* zerobuf, int wid, int lane)
{
    Seg s = segs[0];
    int kloc = kb;
    if (nseg > 1 && kloc >= s.nkb) {
        kloc -= s.nkb; s = segs[1];
        if (nseg > 2 && kloc >= s.nkb) { kloc -= s.nkb; s = segs[2]; }
    }
    int base_row = m0 + s.shift;
    int rvf = base_row < 0 ? -base_row : 0;
    stage_half(ldsA, s.A + (long)base_row * s.astr + kloc * 64, s.astr, rvf,
               zerobuf, wid, lane);
    stage_half(ldsB, s.W + (long)n0 * s.wstr + kloc * 64, s.wstr, 0,
               zerobuf, wid, lane);
}

__device__ __forceinline__ void compute_tile(
    f32x4 acc[4][4], const u16* Ab, const u16* Bb, int wr, int wc, int lane)
{
    const int l15 = lane & 15;
    const int hi = lane >> 4;
#pragma unroll
    for (int ks = 0; ks < 2; ++ks) {
        int kg = ks * 4 + hi;
        short8 a[4], b[4];
#pragma unroll
        for (int am = 0; am < 4; ++am) {
            int row = wr * 64 + am * 16 + l15;
            a[am] = *(const short8*)(Ab + row * 64 + ((kg ^ (row & 7)) << 3));
        }
#pragma unroll
        for (int bn = 0; bn < 4; ++bn) {
            int row = wc * 64 + bn * 16 + l15;
            b[bn] = *(const short8*)(Bb + row * 64 + ((kg ^ (row & 7)) << 3));
        }
#pragma unroll
        for (int am = 0; am < 4; ++am)
#pragma unroll
            for (int bn = 0; bn < 4; ++bn)
                acc[am][bn] = MF(a[am], b[bn], acc[am][bn]);
    }
}

#define GEMM_CORE(SEGS, NSEG, M0, N0W)                                          \
    __shared__ u16 lds[2][2][128 * 64];                                         \
    const int lane = threadIdx.x & 63;                                          \
    const int wid  = threadIdx.x >> 6;                                          \
    const int wr = wid >> 1, wc = wid & 1;                                      \
    f32x4 acc[4][4];                                                            \
    _Pragma("unroll") for (int i_ = 0; i_ < 4; ++i_)                            \
    _Pragma("unroll") for (int j_ = 0; j_ < 4; ++j_)                            \
        acc[i_][j_] = f32x4{0, 0, 0, 0};                                        \
    int nkb = 0;                                                                \
    for (int s_ = 0; s_ < (NSEG); ++s_) nkb += (SEGS)[s_].nkb;                  \
    stage_step((SEGS), (NSEG), 0, lds[0][0], lds[0][1], (M0), (N0W),            \
               zerobuf, wid, lane);                                             \
    int cur = 0;                                                                \
    for (int kb = 0; kb < nkb; ++kb) {                                          \
        __syncthreads();                                                        \
        if (kb + 1 < nkb)                                                       \
            stage_step((SEGS), (NSEG), kb + 1, lds[cur ^ 1][0],                 \
                       lds[cur ^ 1][1], (M0), (N0W), zerobuf, wid, lane);       \
        compute_tile(acc, lds[cur][0], lds[cur][1], wr, wc, lane);              \
        cur ^= 1;                                                               \
    }

// ---------------- e = sigmoid(xw @ w_e^T + b_e), e layout [b*T+t][512] -----
__global__ __launch_bounds__(256) void ekernel(
    const u16* __restrict__ xw, const u16* __restrict__ w_e,
    const float* __restrict__ b_e, u16* __restrict__ eout)
{
    const int lane = threadIdx.x & 63;
    const int wid  = threadIdx.x >> 6;
    const int m0 = blockIdx.x * 64 + (wid >> 1) * 32;
    const int n0 = blockIdx.y * 64 + (wid & 1) * 32;
    f32x4 acc[2][2];
    acc[0][0] = f32x4{0,0,0,0}; acc[0][1] = f32x4{0,0,0,0};
    acc[1][0] = f32x4{0,0,0,0}; acc[1][1] = f32x4{0,0,0,0};
    const int l15 = lane & 15;
    const int klane = (lane >> 4) * 8;
    short8 b0 = *(const short8*)(w_e + (n0 + l15) * Wsz + klane);
    short8 b1 = *(const short8*)(w_e + (n0 + 16 + l15) * Wsz + klane);
#pragma unroll
    for (int am = 0; am < 2; ++am) {
        short8 a = *(const short8*)(xw + (long)(m0 + am * 16 + l15) * Wsz + klane);
        acc[am][0] = MF(a, b0, acc[am][0]);
        acc[am][1] = MF(a, b1, acc[am][1]);
    }
    const int col = lane & 15;
    const int r0 = (lane >> 4) * 4;
#pragma unroll
    for (int am = 0; am < 2; ++am)
#pragma unroll
        for (int bn = 0; bn < 2; ++bn)
#pragma unroll
            for (int i = 0; i < 4; ++i) {
                long row = m0 + am * 16 + r0 + i;
                int g = n0 + bn * 16 + col;
                eout[row * Hsz + g] = f2bf(sigm(acc[am][bn][i] + b_e[g]));
            }
}

// ---------------- pre-pass (r3-exact): pre[b*T+t][group*512 + g] -----------
__global__ __launch_bounds__(256, 2) void prepass_kernel(
    const u16* __restrict__ x, const u16* __restrict__ e,
    const u16* __restrict__ w_d, const u16* __restrict__ w_w,
    const u16* __restrict__ w_m, const u16* __restrict__ w_rx,
    const u16* __restrict__ w_re, const u16* __restrict__ w_zx,
    const u16* __restrict__ w_ze, const u16* __restrict__ w_hx,
    const float* __restrict__ b_r, const float* __restrict__ b_z,
    const float* __restrict__ b_h,
    const u16* __restrict__ zerobuf, u16* __restrict__ pre)
{
    const int m0 = blockIdx.x * 128;
    const int y = blockIdx.y;
    const int group = y >> 2;
    const int nin = (y & 3) * 128;
    Seg segs[3];
    int nseg;
    const float* bias = nullptr;
    if (group == 0) {
        segs[0] = { x, Isz, -1 * Tsz,  w_d, Isz, Isz / 64 };
        segs[1] = { x, Isz, -7 * Tsz,  w_w, Isz, Isz / 64 };
        segs[2] = { x, Isz, -30 * Tsz, w_m, Isz, Isz / 64 };
        nseg = 3;
    } else if (group == 1) {
        segs[0] = { x, Isz, 0, w_rx, Isz, Isz / 64 };
        segs[1] = { e, Hsz, 0, w_re, Hsz, Hsz / 64 };
        nseg = 2; bias = b_r;
    } else if (group == 2) {
        segs[0] = { x, Isz, 0, w_zx, Isz, Isz / 64 };
        segs[1] = { e, Hsz, 0, w_ze, Hsz, Hsz / 64 };
        nseg = 2; bias = b_z;
    } else {
        segs[0] = { x, Isz, 0, w_hx, Isz, Isz / 64 };
        nseg = 1; bias = b_h;
    }
    GEMM_CORE(segs, nseg, m0, nin)
    const int l15 = lane & 15, hi4 = (lane >> 4) * 4;
#pragma unroll
    for (int am = 0; am < 4; ++am)
#pragma unroll
        for (int bn = 0; bn < 4; ++bn) {
            int colH = nin + wc * 64 + bn * 16 + l15;
            float bv = bias ? bias[colH] : 0.0f;
#pragma unroll
            for (int i = 0; i < 4; ++i) {
                long row = m0 + wr * 64 + am * 16 + hi4 + i;
                pre[row * 2048 + group * 512 + colH] = f2bf(acc[am][bn][i] + bv);
            }
        }
}

// ======================= persistent recurrence =============================
// 128 blocks x 1024 thr (16 waves). Block owns 32 batch rows for all 24 steps.
// h/ho/rh in LDS (XOR-swizzled); weights streamed from L2; pre from HBM.
__device__ __forceinline__ int swz(int row, int col) {
    return row * 512 + ((((col >> 3) ^ (row & 7)) << 3) | (col & 7));
}

__device__ __forceinline__ void gemm1(
    f32x4 acc[2][2], const u16* aS, const u16* __restrict__ W, int l15, int hi)
{
    const int rx = l15 & 7;
#pragma unroll 4
    for (int k0 = 0; k0 < 512; k0 += 32) {
        const int ga = (((k0 >> 3) + hi) ^ rx) << 3;
        short8 a0 = *(const short8*)(aS + l15 * 512 + ga);
        short8 a1 = *(const short8*)(aS + (16 + l15) * 512 + ga);
        const u16* wp = W + l15 * 512 + k0 + hi * 8;
        short8 b0 = *(const short8*)(wp);
        short8 b1 = *(const short8*)(wp + 16 * 512);
        acc[0][0] = MF(a0, b0, acc[0][0]);
        acc[0][1] = MF(a0, b1, acc[0][1]);
        acc[1][0] = MF(a1, b0, acc[1][0]);
        acc[1][1] = MF(a1, b1, acc[1][1]);
    }
}

__device__ __forceinline__ void gemm2(
    f32x4 accR[2][2], f32x4 accZ[2][2], const u16* aS,
    const u16* __restrict__ WR, const u16* __restrict__ WZ, int l15, int hi)
{
    const int rx = l15 & 7;
#pragma unroll 2
    for (int k0 = 0; k0 < 512; k0 += 32) {
        const int ga = (((k0 >> 3) + hi) ^ rx) << 3;
        short8 a0 = *(const short8*)(aS + l15 * 512 + ga);
        short8 a1 = *(const short8*)(aS + (16 + l15) * 512 + ga);
        const u16* wpr = WR + l15 * 512 + k0 + hi * 8;
        const u16* wpz = WZ + l15 * 512 + k0 + hi * 8;
        short8 r0 = *(const short8*)(wpr);
        short8 r1 = *(const short8*)(wpr + 16 * 512);
        short8 z0 = *(const short8*)(wpz);
        short8 z1 = *(const short8*)(wpz + 16 * 512);
        accR[0][0] = MF(a0, r0, accR[0][0]);
        accR[0][1] = MF(a0, r1, accR[0][1]);
        accR[1][0] = MF(a1, r0, accR[1][0]);
        accR[1][1] = MF(a1, r1, accR[1][1]);
        accZ[0][0] = MF(a0, z0, accZ[0][0]);
        accZ[0][1] = MF(a0, z1, accZ[0][1]);
        accZ[1][0] = MF(a1, z0, accZ[1][0]);
        accZ[1][1] = MF(a1, z1, accZ[1][1]);
    }
}

#define FOR_FRAG \
    _Pragma("unroll") for (int at = 0; at < 2; ++at) \
    _Pragma("unroll") for (int nt = 0; nt < 2; ++nt) \
    _Pragma("unroll") for (int i = 0; i < 4; ++i)

__global__ __launch_bounds__(1024, 1) void rnn_kernel(
    const u16* __restrict__ pre, const u16* __restrict__ w_t_,
    const u16* __restrict__ w_rh, const u16* __restrict__ w_zh,
    const u16* __restrict__ w_hh, float* __restrict__ out)
{
    __shared__ __align__(16) u16 hS[32 * 512];
    __shared__ __align__(16) u16 aS[32 * 512];
    const int tid = threadIdx.x;
    const int lane = tid & 63;
    const int wave = tid >> 6;
    const int l15 = lane & 15, hi = lane >> 4, hi4 = (lane >> 4) * 4;
    const int n0 = wave * 32;
    const long b0 = (long)blockIdx.x * 32;

    for (int i = tid * 8; i < 32 * 512; i += 1024 * 8)
        *(short8*)(hS + i) = (short8)0;
    __syncthreads();

    const u16* wT = w_t_ + (long)n0 * 512;
    const u16* wR = w_rh + (long)n0 * 512;
    const u16* wZ = w_zh + (long)n0 * 512;
    const u16* wH = w_hh + (long)n0 * 512;

    for (int t = 0; t < Tsz; ++t) {
        // ---- stage A: ho = sigm(pre_o + h @ w_t^T) ----
        float po[2][2][4];
        FOR_FRAG po[at][nt][i] =
            bf2f(pre[((b0 + at * 16 + hi4 + i) * Tsz + t) * 2048
                     + (n0 + nt * 16 + l15)]);
        f32x4 acc[2][2];
        acc[0][0] = f32x4{0,0,0,0}; acc[0][1] = f32x4{0,0,0,0};
        acc[1][0] = f32x4{0,0,0,0}; acc[1][1] = f32x4{0,0,0,0};
        gemm1(acc, hS, wT, l15, hi);
        float hov[2][2][4];
        FOR_FRAG {
            int row = at * 16 + hi4 + i, col = n0 + nt * 16 + l15;
            float v = sigm(acc[at][nt][i] + po[at][nt][i]);
            hov[at][nt][i] = v;
            aS[swz(row, col)] = f2bf(v);
        }
        __syncthreads();

        // ---- stage B: r,z = sigm(pre + ho @ w^T); rh = r*ho ----
        float pr[2][2][4], pz[2][2][4];
        FOR_FRAG {
            long prow = ((b0 + at * 16 + hi4 + i) * Tsz + t) * 2048;
            int col = n0 + nt * 16 + l15;
            pr[at][nt][i] = bf2f(pre[prow + 512 + col]);
            pz[at][nt][i] = bf2f(pre[prow + 1024 + col]);
        }
        f32x4 accR[2][2], accZ[2][2];
        accR[0][0] = f32x4{0,0,0,0}; accR[0][1] = f32x4{0,0,0,0};
        accR[1][0] = f32x4{0,0,0,0}; accR[1][1] = f32x4{0,0,0,0};
        accZ[0][0] = f32x4{0,0,0,0}; accZ[0][1] = f32x4{0,0,0,0};
        accZ[1][0] = f32x4{0,0,0,0}; accZ[1][1] = f32x4{0,0,0,0};
        gemm2(accR, accZ, aS, wR, wZ, l15, hi);
        float zv[2][2][4], rh[2][2][4];
        FOR_FRAG {
            zv[at][nt][i] = sigm(accZ[at][nt][i] + pz[at][nt][i]);
            rh[at][nt][i] = sigm(accR[at][nt][i] + pr[at][nt][i]) * hov[at][nt][i];
        }
        __syncthreads();  // all waves done reading aS (=ho)
        FOR_FRAG {
            int row = at * 16 + hi4 + i, col = n0 + nt * 16 + l15;
            aS[swz(row, col)] = f2bf(rh[at][nt][i]);
        }
        __syncthreads();  // aS (=rh) ready

        // ---- stage C: h~ = tanh(pre_h + rh @ w_hh^T); h = (1-z)ho + z h~ ----
        float ph[2][2][4];
        FOR_FRAG ph[at][nt][i] =
            bf2f(pre[((b0 + at * 16 + hi4 + i) * Tsz + t) * 2048
                     + 1536 + (n0 + nt * 16 + l15)]);
        f32x4 accH[2][2];
        accH[0][0] = f32x4{0,0,0,0}; accH[0][1] = f32x4{0,0,0,0};
        accH[1][0] = f32x4{0,0,0,0}; accH[1][1] = f32x4{0,0,0,0};
        gemm1(accH, aS, wH, l15, hi);
        FOR_FRAG {
            int row = at * 16 + hi4 + i, col = n0 + nt * 16 + l15;
            float htl = tanhf(accH[at][nt][i] + ph[at][nt][i]);
            float z = zv[at][nt][i];
            float hn = (1.0f - z) * hov[at][nt][i] + z * htl;
            out[((b0 + row) * Tsz + t) * (long)Hsz + col] = hn;
            hS[swz(row, col)] = f2bf(hn);
        }
        __syncthreads();  // hS ready; aS reads done before next overwrite
    }
}

extern "C" void kernel_launch(void* const* d_in, const int* in_sizes, int n_in,
                              void* d_out, int out_size, void* d_ws, size_t ws_size,
                              hipStream_t stream) {
    const float* x_f    = (const float*)d_in[0];
    const float* xw_f   = (const float*)d_in[1];
    const float* w_rx_f = (const float*)d_in[2];
    const float* w_rh_f = (const float*)d_in[3];
    const float* w_re_f = (const float*)d_in[4];
    const float* b_r    = (const float*)d_in[5];
    const float* w_zx_f = (const float*)d_in[6];
    const float* w_zh_f = (const float*)d_in[7];
    const float* w_ze_f = (const float*)d_in[8];
    const float* b_z    = (const float*)d_in[9];
    const float* w_hx_f = (const float*)d_in[10];
    const float* w_hh_f = (const float*)d_in[11];
    const float* b_h    = (const float*)d_in[12];
    const float* w_d_f  = (const float*)d_in[13];
    const float* w_w_f  = (const float*)d_in[14];
    const float* w_m_f  = (const float*)d_in[15];
    const float* w_t_f  = (const float*)d_in[16];
    const float* w_e_f  = (const float*)d_in[17];
    const float* b_e    = (const float*)d_in[18];
    float* out = (float*)d_out;

    char* ws = (char*)d_ws;
    size_t off = 0;
    auto alloc = [&](size_t bytes) {
        size_t o = off; off = (off + bytes + 255) & ~(size_t)255; return o;
    };
    const size_t nx  = (size_t)Msz * Isz;
    const size_t nxw = (size_t)Msz * Wsz;

    u16* x_bf  = (u16*)(ws + alloc(nx * 2));
    u16* xw_bf = (u16*)(ws + alloc(nxw * 2));
    u16* w_rx  = (u16*)(ws + alloc(Hsz * Isz * 2));
    u16* w_rh  = (u16*)(ws + alloc(Hsz * Hsz * 2));
    u16* w_re  = (u16*)(ws + alloc(Hsz * Hsz * 2));
    u16* w_zx  = (u16*)(ws + alloc(Hsz * Isz * 2));
    u16* w_zh  = (u16*)(ws + alloc(Hsz * Hsz * 2));
    u16* w_ze  = (u16*)(ws + alloc(Hsz * Hsz * 2));
    u16* w_hx  = (u16*)(ws + alloc(Hsz * Isz * 2));
    u16* w_hh  = (u16*)(ws + alloc(Hsz * Hsz * 2));
    u16* w_d   = (u16*)(ws + alloc(Hsz * Isz * 2));
    u16* w_w   = (u16*)(ws + alloc(Hsz * Isz * 2));
    u16* w_m   = (u16*)(ws + alloc(Hsz * Isz * 2));
    u16* w_t   = (u16*)(ws + alloc(Hsz * Hsz * 2));
    u16* w_e   = (u16*)(ws + alloc(Hsz * Wsz * 2));
    u16* e_bf  = (u16*)(ws + alloc((size_t)Msz * Hsz * 2));   // 96 MB [b*T+t]
    u16* pre   = (u16*)(ws + alloc((size_t)Msz * 2048 * 2));  // 384 MB [b*T+t]
    u16* zerobuf = (u16*)(ws + alloc(256));

    convert_big<<<(int)(nx / 1024), 256, 0, stream>>>(x_f, x_bf, (int)nx);
    convert_big<<<(int)(nxw / 1024), 256, 0, stream>>>(xw_f, xw_bf, (int)nxw);
    ConvTab tab;
    tab.d[0]  = { w_rx_f, w_rx, Hsz * Isz };
    tab.d[1]  = { w_rh_f, w_rh, Hsz * Hsz };
    tab.d[2]  = { w_re_f, w_re, Hsz * Hsz };
    tab.d[3]  = { w_zx_f, w_zx, Hsz * Isz };
    tab.d[4]  = { w_zh_f, w_zh, Hsz * Hsz };
    tab.d[5]  = { w_ze_f, w_ze, Hsz * Hsz };
    tab.d[6]  = { w_hx_f, w_hx, Hsz * Isz };
    tab.d[7]  = { w_hh_f, w_hh, Hsz * Hsz };
    tab.d[8]  = { w_d_f,  w_d,  Hsz * Isz };
    tab.d[9]  = { w_w_f,  w_w,  Hsz * Isz };
    tab.d[10] = { w_m_f,  w_m,  Hsz * Isz };
    tab.d[11] = { w_t_f,  w_t,  Hsz * Hsz };
    tab.d[12] = { w_e_f,  w_e,  Hsz * Wsz };
    convert_many<<<dim3(256, 13), 256, 0, stream>>>(tab);
    hipMemsetAsync(zerobuf, 0, 256, stream);

    // e = sigmoid(xw @ w_e^T + b_e)  [98304 x 512], layout [b*T+t]
    ekernel<<<dim3(Msz / 64, Hsz / 64), 256, 0, stream>>>(xw_bf, w_e, b_e, e_bf);

    // pre-pass: all input-only projections [98304 x 2048], layout [b*T+t]
    prepass_kernel<<<dim3(Msz / 128, 16), 256, 0, stream>>>(
        x_bf, e_bf, w_d, w_w, w_m, w_rx, w_re, w_zx, w_ze, w_hx,
        b_r, b_z, b_h, zerobuf, pre);

    // persistent recurrence: whole T-loop in one kernel
    rnn_kernel<<<Bsz / 32, 1024, 0, stream>>>(pre, w_t, w_rh, w_zh, w_hh, out);
}